// Round 1
// baseline (834.709 us; speedup 1.0000x reference)
//
#include <hip/hip_runtime.h>
#include <math.h>

#define HW 6400

__device__ __forceinline__ float wredsum(float v){
  #pragma unroll
  for (int o = 32; o; o >>= 1) v += __shfl_xor(v, o);
  return v;
}

// ---------------- K1: depthwise dilated convs + GN partial stats ----------------
__global__ __launch_bounds__(256) void k_dw(
    const float* __restrict__ z,
    const float* __restrict__ w0, const float* __restrict__ b0,
    const float* __restrict__ w1, const float* __restrict__ b1,
    const float* __restrict__ w2, const float* __restrict__ b2,
    const float* __restrict__ w3, const float* __restrict__ b3,
    float* __restrict__ zc, float* __restrict__ gnpart){
  int tid = threadIdx.x;
  int c = blockIdx.y, b = blockIdx.z;
  int pix = blockIdx.x * 256 + tid;
  int h = pix / 80, w = pix % 80;
  int part = c >> 6, cl = c & 63;
  const float* wp; const float* bp; int d;
  if (part == 0)      { wp = w0; bp = b0; d = 7; }
  else if (part == 1) { wp = w1; bp = b1; d = 5; }
  else if (part == 2) { wp = w2; bp = b2; d = 2; }
  else                { wp = w3; bp = b3; d = 1; }
  wp += cl * 9;
  const float* zin = z + (b * 256 + c) * HW;
  float acc = bp[cl];
  #pragma unroll
  for (int kh = 0; kh < 3; kh++){
    int hh = h + (kh - 1) * d;
    if ((unsigned)hh < 80u){
      #pragma unroll
      for (int kw = 0; kw < 3; kw++){
        int ww = w + (kw - 1) * d;
        if ((unsigned)ww < 80u) acc += wp[kh * 3 + kw] * zin[hh * 80 + ww];
      }
    }
  }
  zc[(b * 256 + c) * HW + pix] = acc;
  float S = wredsum(acc), Q = wredsum(acc * acc);
  __shared__ float l[8];
  int lane = tid & 63, wid = tid >> 6;
  if (lane == 0){ l[wid] = S; l[4 + wid] = Q; }
  __syncthreads();
  if (tid == 0){
    float SS = l[0] + l[1] + l[2] + l[3];
    float QQ = l[4] + l[5] + l[6] + l[7];
    int blkid = (b * 256 + c) * 25 + blockIdx.x;
    gnpart[blkid * 2] = SS; gnpart[blkid * 2 + 1] = QQ;
  }
}

// ---------------- K2: GN stats finalize -> per (b,c) scale/shift ----------------
__global__ __launch_bounds__(256) void k_gnfin(
    const float* __restrict__ gnpart, const float* __restrict__ gn_w,
    const float* __restrict__ gn_b, float* __restrict__ gn_sc){
  int tid = threadIdx.x; int bg = blockIdx.x; // b*4+g
  float S = 0.f, Q = 0.f;
  for (int i = tid; i < 1600; i += 256){
    S += gnpart[(bg * 1600 + i) * 2];
    Q += gnpart[(bg * 1600 + i) * 2 + 1];
  }
  S = wredsum(S); Q = wredsum(Q);
  __shared__ float l[8];
  int lane = tid & 63, wid = tid >> 6;
  if (lane == 0){ l[wid] = S; l[4 + wid] = Q; }
  __syncthreads();
  float SS = l[0] + l[1] + l[2] + l[3];
  float QQ = l[4] + l[5] + l[6] + l[7];
  float M = 64.f * HW;
  float mean = SS / M;
  float var = QQ / M - mean * mean;
  float rstd = rsqrtf(var + 1e-5f);
  if (tid < 64){
    int b = bg >> 2, g = bg & 3;
    int c = g * 64 + tid;
    float sc = gn_w[c] * rstd;
    float sh = gn_b[c] - mean * sc;
    gn_sc[(b * 256 + c) * 2] = sc;
    gn_sc[(b * 256 + c) * 2 + 1] = sh;
  }
}

// ---------------- K3: GN-apply + 1x1 conv (256->256) + bias + GELU ----------------
__global__ __launch_bounds__(256) void k_conv1(
    const float* __restrict__ zc, const float* __restrict__ gn_sc,
    const float* __restrict__ cw, const float* __restrict__ cb,
    float* __restrict__ zc2){
  int tid = threadIdx.x;
  int pix = blockIdx.x * 256 + tid;
  int ot = blockIdx.y * 32;
  int b = blockIdx.z;
  float acc[32];
  #pragma unroll
  for (int o = 0; o < 32; o++) acc[o] = 0.f;
  for (int c0 = 0; c0 < 256; c0 += 16){
    float xv[16];
    #pragma unroll
    for (int cc = 0; cc < 16; cc++){
      int c = c0 + cc;
      float sc = gn_sc[(b * 256 + c) * 2], sh = gn_sc[(b * 256 + c) * 2 + 1];
      xv[cc] = zc[(b * 256 + c) * HW + pix] * sc + sh;
    }
    #pragma unroll
    for (int o = 0; o < 32; o++){
      const float* wr = cw + (ot + o) * 256 + c0;
      float a = acc[o];
      #pragma unroll
      for (int cc = 0; cc < 16; cc++) a += wr[cc] * xv[cc];
      acc[o] = a;
    }
  }
  #pragma unroll
  for (int o = 0; o < 32; o++){
    float v = acc[o] + cb[ot + o];
    v = 0.5f * v * (1.f + erff(v * 0.70710678118f));
    zc2[(b * 256 + ot + o) * HW + pix] = v;
  }
}

// ---------------- K4: 3x3 conv 256->32 (c5a|c5c fused) + BN partial stats ----------------
__global__ __launch_bounds__(256) void k_conv5ac(
    const float* __restrict__ zc2, const float* __restrict__ wa,
    const float* __restrict__ wc, float* __restrict__ fpre,
    float* __restrict__ bnpart){
  __shared__ float lx[8 * 324];
  __shared__ float lred[4 * 16];
  int tid = threadIdx.x;
  int w0 = blockIdx.x * 16, h0 = blockIdx.y * 16;
  int bz = blockIdx.z; int b = bz >> 2, ocg = bz & 3;
  int ph = tid >> 4, pw = tid & 15;
  const float* wsel = (ocg < 2) ? wa : wc;
  int olocal = (ocg & 1) * 8;
  float acc[8];
  #pragma unroll
  for (int o = 0; o < 8; o++) acc[o] = 0.f;
  for (int c0 = 0; c0 < 256; c0 += 8){
    __syncthreads();
    for (int i = tid; i < 2592; i += 256){
      int cc = i / 324, r = i - cc * 324;
      int y = r / 18, x = r - y * 18;
      int gh = h0 - 1 + y, gw = w0 - 1 + x;
      float v = 0.f;
      if ((unsigned)gh < 80u && (unsigned)gw < 80u)
        v = zc2[(b * 256 + c0 + cc) * HW + gh * 80 + gw];
      lx[i] = v;
    }
    __syncthreads();
    #pragma unroll
    for (int cc = 0; cc < 8; cc++){
      float xv[9];
      #pragma unroll
      for (int dy = 0; dy < 3; dy++)
        #pragma unroll
        for (int dx = 0; dx < 3; dx++)
          xv[dy * 3 + dx] = lx[cc * 324 + (ph + dy) * 18 + (pw + dx)];
      #pragma unroll
      for (int o = 0; o < 8; o++){
        const float* wr = wsel + ((olocal + o) * 256 + c0 + cc) * 9;
        float a = acc[o];
        #pragma unroll
        for (int k = 0; k < 9; k++) a += wr[k] * xv[k];
        acc[o] = a;
      }
    }
  }
  int oc0 = ocg * 8;
  int pix = (h0 + ph) * 80 + (w0 + pw);
  int lane = tid & 63, wid = tid >> 6;
  int tile = blockIdx.y * 5 + blockIdx.x;
  #pragma unroll
  for (int o = 0; o < 8; o++){
    fpre[(b * 32 + oc0 + o) * HW + pix] = acc[o];
    float S = wredsum(acc[o]), Q = wredsum(acc[o] * acc[o]);
    if (lane == 0){ lred[wid * 16 + o * 2] = S; lred[wid * 16 + o * 2 + 1] = Q; }
  }
  __syncthreads();
  if (tid < 16){
    int o = tid >> 1, j = tid & 1;
    float s = lred[0 * 16 + o * 2 + j] + lred[1 * 16 + o * 2 + j] +
              lred[2 * 16 + o * 2 + j] + lred[3 * 16 + o * 2 + j];
    int oc = oc0 + o;
    bnpart[oc * 100 + (b * 25 + tile) * 2 + j] = s;
  }
}

// ---------------- K5/K12: BN finalize (32 channels, two halves) ----------------
__global__ void k_bnfin(
    const float* __restrict__ part,
    const float* __restrict__ w1, const float* __restrict__ b1,
    const float* __restrict__ w2, const float* __restrict__ b2,
    float* __restrict__ sc_out){
  int oc = threadIdx.x; if (oc >= 32) return;
  float S = 0.f, Q = 0.f;
  for (int i = 0; i < 50; i++){
    S += part[oc * 100 + i * 2];
    Q += part[oc * 100 + i * 2 + 1];
  }
  float M = 2.f * HW;
  float mean = S / M, var = Q / M - mean * mean;
  float rstd = rsqrtf(var + 1e-3f);
  float w  = (oc < 16) ? w1[oc] : w2[oc - 16];
  float bb = (oc < 16) ? b1[oc] : b2[oc - 16];
  float sc = w * rstd, sh = bb - mean * sc;
  sc_out[oc * 2] = sc; sc_out[oc * 2 + 1] = sh;
}

// ---------------- K6: BN+relu apply -> feat1/feat2, and q,k,v 1x1 convs ----------------
__global__ __launch_bounds__(256) void k_featqkv(
    const float* __restrict__ fpre, const float* __restrict__ bnsc,
    const float* __restrict__ pqw, const float* __restrict__ pqb,
    const float* __restrict__ pkw, const float* __restrict__ pkb,
    const float* __restrict__ pvw, const float* __restrict__ pvb,
    float* __restrict__ feat, float* __restrict__ qkvT){
  int tid = threadIdx.x; int b = blockIdx.y;
  int n = blockIdx.x * 256 + tid;
  float f1[16], f2[16];
  #pragma unroll
  for (int c = 0; c < 16; c++){
    float v1 = fpre[(b * 32 + c) * HW + n] * bnsc[c * 2] + bnsc[c * 2 + 1];
    f1[c] = fmaxf(v1, 0.f);
    float v2 = fpre[(b * 32 + 16 + c) * HW + n] * bnsc[(16 + c) * 2] + bnsc[(16 + c) * 2 + 1];
    f2[c] = fmaxf(v2, 0.f);
    feat[(b * 32 + c) * HW + n] = f1[c];
    feat[(b * 32 + 16 + c) * HW + n] = f2[c];
  }
  float* o = qkvT + ((size_t)b * HW + n) * 20;
  #pragma unroll
  for (int j = 0; j < 2; j++){
    float q = pqb[j], k = pkb[j];
    #pragma unroll
    for (int c = 0; c < 16; c++){ q += pqw[j * 16 + c] * f1[c]; k += pkw[j * 16 + c] * f1[c]; }
    o[j] = q; o[2 + j] = k;
  }
  #pragma unroll
  for (int j = 0; j < 16; j++){
    float v = pvb[j];
    #pragma unroll
    for (int c = 0; c < 16; c++) v += pvw[j * 16 + c] * f1[c];
    o[4 + j] = v;
  }
}

// ---------------- K7a: PAM flash partials over m-chunks ----------------
__global__ __launch_bounds__(256) void k_pam_a(
    const float* __restrict__ qkvT, float* __restrict__ part){
  int tid = threadIdx.x;
  int n = blockIdx.x * 256 + tid;
  int mc = blockIdx.y, b = blockIdx.z;
  const float* qp = qkvT + ((size_t)b * HW + n) * 20;
  float q0 = qp[0], q1 = qp[1];
  float mx = -1e30f, Z = 0.f;
  float acc[16];
  #pragma unroll
  for (int c = 0; c < 16; c++) acc[c] = 0.f;
  const float* kvbase = qkvT + ((size_t)b * HW + mc * 800) * 20;
  for (int mi = 0; mi < 800; mi++){
    const float* kv = kvbase + mi * 20;          // uniform across block -> scalar loads
    float k0 = kv[2], k1 = kv[3];
    float s = q0 * k0 + q1 * k1;
    if (s <= mx){
      float p = __expf(s - mx);
      Z += p;
      #pragma unroll
      for (int c = 0; c < 16; c++) acc[c] += p * kv[4 + c];
    } else {
      float r = __expf(mx - s);
      mx = s;
      Z = Z * r + 1.f;
      #pragma unroll
      for (int c = 0; c < 16; c++) acc[c] = acc[c] * r + kv[4 + c];
    }
  }
  float* pp = part + ((size_t)(b * 8 + mc) * 18) * HW + n;
  pp[0] = mx; pp[HW] = Z;
  #pragma unroll
  for (int c = 0; c < 16; c++) pp[(size_t)(2 + c) * HW] = acc[c];
}

// ---------------- K7b: merge PAM partials, residual ----------------
__global__ __launch_bounds__(256) void k_pam_b(
    const float* __restrict__ part, const float* __restrict__ feat,
    const float* __restrict__ gammap, float* __restrict__ pam_in){
  int tid = threadIdx.x; int b = blockIdx.y;
  int n = blockIdx.x * 256 + tid;
  float gamma = gammap[0];
  float mxs[8]; float mx = -1e30f;
  #pragma unroll
  for (int mc = 0; mc < 8; mc++){
    mxs[mc] = part[((size_t)(b * 8 + mc) * 18) * HW + n];
    mx = fmaxf(mx, mxs[mc]);
  }
  float Z = 0.f, acc[16];
  #pragma unroll
  for (int c = 0; c < 16; c++) acc[c] = 0.f;
  #pragma unroll
  for (int mc = 0; mc < 8; mc++){
    const float* pp = part + ((size_t)(b * 8 + mc) * 18) * HW + n;
    float r = __expf(mxs[mc] - mx);
    Z += pp[HW] * r;
    #pragma unroll
    for (int c = 0; c < 16; c++) acc[c] += pp[(size_t)(2 + c) * HW] * r;
  }
  float inv = 1.f / Z;
  #pragma unroll
  for (int c = 0; c < 16; c++){
    float pa = acc[c] * inv;
    pam_in[(b * 16 + c) * HW + n] = gamma * pa + feat[(b * 32 + c) * HW + n];
  }
}

// ---------------- K8: CAM gram matrix e[b,c,d] ----------------
__global__ __launch_bounds__(256) void k_cam_gram(
    const float* __restrict__ feat, float* __restrict__ e){
  int tid = threadIdx.x;
  int dd = blockIdx.x, c = blockIdx.y, b = blockIdx.z;
  const float* fc = feat + (b * 32 + 16 + c) * HW;
  const float* fd = feat + (b * 32 + 16 + dd) * HW;
  float S = 0.f;
  for (int i = tid; i < HW; i += 256) S += fc[i] * fd[i];
  S = wredsum(S);
  __shared__ float l[4];
  int lane = tid & 63, wid = tid >> 6;
  if (lane == 0) l[wid] = S;
  __syncthreads();
  if (tid == 0) e[(b * 16 + c) * 16 + dd] = l[0] + l[1] + l[2] + l[3];
}

// ---------------- K9: CAM softmax of (max - e) rows ----------------
__global__ void k_cam_soft(const float* __restrict__ e, float* __restrict__ att){
  int tid = threadIdx.x; if (tid >= 32) return;
  int b = tid >> 4, c = tid & 15;
  const float* row = e + (b * 16 + c) * 16;
  float r[16]; float mn = 1e30f;
  #pragma unroll
  for (int d = 0; d < 16; d++){ r[d] = row[d]; mn = fminf(mn, r[d]); }
  float p[16]; float s = 0.f;
  #pragma unroll
  for (int d = 0; d < 16; d++){ p[d] = __expf(mn - r[d]); s += p[d]; }
  float inv = 1.f / s;
  #pragma unroll
  for (int d = 0; d < 16; d++) att[(b * 16 + c) * 16 + d] = p[d] * inv;
}

// ---------------- K10: CAM apply + residual ----------------
__global__ __launch_bounds__(256) void k_cam_apply(
    const float* __restrict__ att, const float* __restrict__ feat,
    const float* __restrict__ gammap, float* __restrict__ cam_in){
  int tid = threadIdx.x; int c = blockIdx.y, b = blockIdx.z;
  int n = blockIdx.x * 256 + tid;
  const float* arow = att + (b * 16 + c) * 16;
  float s = 0.f;
  #pragma unroll
  for (int d = 0; d < 16; d++) s += arow[d] * feat[(b * 32 + 16 + d) * HW + n];
  cam_in[(b * 16 + c) * HW + n] = gammap[0] * s + feat[(b * 32 + 16 + c) * HW + n];
}

// ---------------- K11: 3x3 conv 16->32 (c5b on pam | c5d on cam) + BN stats ----------------
__global__ __launch_bounds__(256) void k_conv5bd(
    const float* __restrict__ pam_in, const float* __restrict__ cam_in,
    const float* __restrict__ wb, const float* __restrict__ wd,
    float* __restrict__ bdpre, float* __restrict__ bnpart){
  __shared__ float lx[16 * 324];
  __shared__ float lred[4 * 16];
  int tid = threadIdx.x;
  int w0 = blockIdx.x * 16, h0 = blockIdx.y * 16;
  int bz = blockIdx.z; int b = bz >> 2, ocg = bz & 3;
  const float* in = ((ocg < 2) ? pam_in : cam_in) + b * 16 * HW;
  const float* wsel = (ocg < 2) ? wb : wd;
  int olocal = (ocg & 1) * 8;
  int ph = tid >> 4, pw = tid & 15;
  for (int i = tid; i < 16 * 324; i += 256){
    int cc = i / 324, r = i - cc * 324;
    int y = r / 18, x = r - y * 18;
    int gh = h0 - 1 + y, gw = w0 - 1 + x;
    float v = 0.f;
    if ((unsigned)gh < 80u && (unsigned)gw < 80u) v = in[cc * HW + gh * 80 + gw];
    lx[i] = v;
  }
  __syncthreads();
  float acc[8];
  #pragma unroll
  for (int o = 0; o < 8; o++) acc[o] = 0.f;
  #pragma unroll
  for (int cc = 0; cc < 16; cc++){
    float xv[9];
    #pragma unroll
    for (int dy = 0; dy < 3; dy++)
      #pragma unroll
      for (int dx = 0; dx < 3; dx++)
        xv[dy * 3 + dx] = lx[cc * 324 + (ph + dy) * 18 + (pw + dx)];
    #pragma unroll
    for (int o = 0; o < 8; o++){
      const float* wr = wsel + ((olocal + o) * 16 + cc) * 9;
      float a = acc[o];
      #pragma unroll
      for (int k = 0; k < 9; k++) a += wr[k] * xv[k];
      acc[o] = a;
    }
  }
  int oc0 = ocg * 8;
  int pix = (h0 + ph) * 80 + (w0 + pw);
  int lane = tid & 63, wid = tid >> 6;
  int tile = blockIdx.y * 5 + blockIdx.x;
  #pragma unroll
  for (int o = 0; o < 8; o++){
    bdpre[(b * 32 + oc0 + o) * HW + pix] = acc[o];
    float S = wredsum(acc[o]), Q = wredsum(acc[o] * acc[o]);
    if (lane == 0){ lred[wid * 16 + o * 2] = S; lred[wid * 16 + o * 2 + 1] = Q; }
  }
  __syncthreads();
  if (tid < 16){
    int o = tid >> 1, j = tid & 1;
    float s = lred[0 * 16 + o * 2 + j] + lred[1 * 16 + o * 2 + j] +
              lred[2 * 16 + o * 2 + j] + lred[3 * 16 + o * 2 + j];
    int oc = oc0 + o;
    bnpart[oc * 100 + (b * 25 + tile) * 2 + j] = s;
  }
}

// ---------------- K13: BN+relu both halves, sum ----------------
__global__ __launch_bounds__(256) void k_ssum(
    const float* __restrict__ bdpre, const float* __restrict__ bnsc,
    float* __restrict__ ssum){
  int tid = threadIdx.x; int c = blockIdx.y, b = blockIdx.z;
  int n = blockIdx.x * 256 + tid;
  float v1 = bdpre[(b * 32 + c) * HW + n] * bnsc[c * 2] + bnsc[c * 2 + 1];
  float v2 = bdpre[(b * 32 + 16 + c) * HW + n] * bnsc[(16 + c) * 2] + bnsc[(16 + c) * 2 + 1];
  ssum[(b * 16 + c) * HW + n] = fmaxf(v1, 0.f) + fmaxf(v2, 0.f);
}

// ---------------- K14: 1x1 conv 16->256 + bias + relu -> out ----------------
__global__ __launch_bounds__(256) void k_c6(
    const float* __restrict__ ssum, const float* __restrict__ w6,
    const float* __restrict__ b6, float* __restrict__ out){
  int tid = threadIdx.x; int og = blockIdx.y * 4, b = blockIdx.z;
  int n = blockIdx.x * 256 + tid;
  float x[16];
  #pragma unroll
  for (int c = 0; c < 16; c++) x[c] = ssum[(b * 16 + c) * HW + n];
  #pragma unroll
  for (int o = 0; o < 4; o++){
    float a = b6[og + o];
    #pragma unroll
    for (int c = 0; c < 16; c++) a += w6[(og + o) * 16 + c] * x[c];
    out[(b * 256 + og + o) * HW + n] = fmaxf(a, 0.f);
  }
}

extern "C" void kernel_launch(void* const* d_in, const int* in_sizes, int n_in,
                              void* d_out, int out_size, void* d_ws, size_t ws_size,
                              hipStream_t stream){
  const float* z      = (const float*)d_in[0];
  const float* w_at0  = (const float*)d_in[1];
  const float* b_at0  = (const float*)d_in[2];
  const float* w_at1  = (const float*)d_in[3];
  const float* b_at1  = (const float*)d_in[4];
  const float* w_at2  = (const float*)d_in[5];
  const float* b_at2  = (const float*)d_in[6];
  const float* w_at3  = (const float*)d_in[7];
  const float* b_at3  = (const float*)d_in[8];
  const float* gn_w   = (const float*)d_in[9];
  const float* gn_b   = (const float*)d_in[10];
  const float* conv_w = (const float*)d_in[11];
  const float* conv_b = (const float*)d_in[12];
  const float* c5a_w  = (const float*)d_in[13];
  const float* bn5a_w = (const float*)d_in[14];
  const float* bn5a_b = (const float*)d_in[15];
  const float* c5c_w  = (const float*)d_in[16];
  const float* bn5c_w = (const float*)d_in[17];
  const float* bn5c_b = (const float*)d_in[18];
  const float* pq_w   = (const float*)d_in[19];
  const float* pq_b   = (const float*)d_in[20];
  const float* pk_w   = (const float*)d_in[21];
  const float* pk_b   = (const float*)d_in[22];
  const float* pv_w   = (const float*)d_in[23];
  const float* pv_b   = (const float*)d_in[24];
  const float* pa_g   = (const float*)d_in[25];
  const float* ca_g   = (const float*)d_in[26];
  const float* c5b_w  = (const float*)d_in[27];
  const float* bn5b_w = (const float*)d_in[28];
  const float* bn5b_b = (const float*)d_in[29];
  const float* c5d_w  = (const float*)d_in[30];
  const float* bn5d_w = (const float*)d_in[31];
  const float* bn5d_b = (const float*)d_in[32];
  const float* c6_w   = (const float*)d_in[33];
  const float* c6_b   = (const float*)d_in[34];

  float* ws = (float*)d_ws;
  float* ZC      = ws;                    // 3,276,800 (aliased later as PART)
  float* ZC2     = ZC + 3276800;          // 3,276,800
  float* FPRE    = ZC2 + 3276800;         // 409,600
  float* FEAT    = FPRE + 409600;         // 409,600
  float* QKVT    = FEAT + 409600;         // 256,000
  float* PAM_IN  = QKVT + 256000;         // 204,800
  float* CAM_IN  = PAM_IN + 204800;       // 204,800
  float* BDPRE   = CAM_IN + 204800;       // 409,600
  float* SSUM    = BDPRE + 409600;        // 204,800
  float* ST      = SSUM + 204800;
  float* GN_SC    = ST;                   // 1024
  float* BNA_SC   = ST + 1024;            // 64
  float* BNB_SC   = ST + 1088;            // 64
  float* CAM_ATT  = ST + 1152;            // 512
  float* CAM_E    = ST + 1664;            // 512
  float* GN_PART  = ST + 2176;            // 25,600
  float* BNA_PART = ST + 27776;           // 3,200
  float* BNB_PART = ST + 30976;           // 3,200
  float* PART = ZC;                       // alias: ZC dead after k_conv1

  k_dw<<<dim3(25, 256, 2), 256, 0, stream>>>(z, w_at0, b_at0, w_at1, b_at1,
                                             w_at2, b_at2, w_at3, b_at3, ZC, GN_PART);
  k_gnfin<<<8, 256, 0, stream>>>(GN_PART, gn_w, gn_b, GN_SC);
  k_conv1<<<dim3(25, 8, 2), 256, 0, stream>>>(ZC, GN_SC, conv_w, conv_b, ZC2);
  k_conv5ac<<<dim3(5, 5, 8), 256, 0, stream>>>(ZC2, c5a_w, c5c_w, FPRE, BNA_PART);
  k_bnfin<<<1, 32, 0, stream>>>(BNA_PART, bn5a_w, bn5a_b, bn5c_w, bn5c_b, BNA_SC);
  k_featqkv<<<dim3(25, 2), 256, 0, stream>>>(FPRE, BNA_SC, pq_w, pq_b, pk_w, pk_b,
                                             pv_w, pv_b, FEAT, QKVT);
  k_pam_a<<<dim3(25, 8, 2), 256, 0, stream>>>(QKVT, PART);
  k_pam_b<<<dim3(25, 2), 256, 0, stream>>>(PART, FEAT, pa_g, PAM_IN);
  k_cam_gram<<<dim3(16, 16, 2), 256, 0, stream>>>(FEAT, CAM_E);
  k_cam_soft<<<1, 64, 0, stream>>>(CAM_E, CAM_ATT);
  k_cam_apply<<<dim3(25, 16, 2), 256, 0, stream>>>(CAM_ATT, FEAT, ca_g, CAM_IN);
  k_conv5bd<<<dim3(5, 5, 8), 256, 0, stream>>>(PAM_IN, CAM_IN, c5b_w, c5d_w, BDPRE, BNB_PART);
  k_bnfin<<<1, 32, 0, stream>>>(BNB_PART, bn5b_w, bn5b_b, bn5d_w, bn5d_b, BNB_SC);
  k_ssum<<<dim3(25, 16, 2), 256, 0, stream>>>(BDPRE, BNB_SC, SSUM);
  k_c6<<<dim3(25, 64, 2), 256, 0, stream>>>(SSUM, c6_w, c6_b, (float*)d_out);
}

// Round 2
// 605.794 us; speedup vs baseline: 1.3779x; 1.3779x over previous
//
#include <hip/hip_runtime.h>
#include <math.h>

#define HW 6400

__device__ __forceinline__ float wredsum(float v){
  #pragma unroll
  for (int o = 32; o; o >>= 1) v += __shfl_xor(v, o);
  return v;
}

// ---------------- K1: depthwise dilated convs + GN partial stats ----------------
__global__ __launch_bounds__(256) void k_dw(
    const float* __restrict__ z,
    const float* __restrict__ w0, const float* __restrict__ b0,
    const float* __restrict__ w1, const float* __restrict__ b1,
    const float* __restrict__ w2, const float* __restrict__ b2,
    const float* __restrict__ w3, const float* __restrict__ b3,
    float* __restrict__ zc, float* __restrict__ gnpart){
  int tid = threadIdx.x;
  int c = blockIdx.y, b = blockIdx.z;
  int pix = blockIdx.x * 256 + tid;
  int h = pix / 80, w = pix % 80;
  int part = c >> 6, cl = c & 63;
  const float* wp; const float* bp; int d;
  if (part == 0)      { wp = w0; bp = b0; d = 7; }
  else if (part == 1) { wp = w1; bp = b1; d = 5; }
  else if (part == 2) { wp = w2; bp = b2; d = 2; }
  else                { wp = w3; bp = b3; d = 1; }
  wp += cl * 9;
  const float* zin = z + (b * 256 + c) * HW;
  float acc = bp[cl];
  #pragma unroll
  for (int kh = 0; kh < 3; kh++){
    int hh = h + (kh - 1) * d;
    if ((unsigned)hh < 80u){
      #pragma unroll
      for (int kw = 0; kw < 3; kw++){
        int ww = w + (kw - 1) * d;
        if ((unsigned)ww < 80u) acc += wp[kh * 3 + kw] * zin[hh * 80 + ww];
      }
    }
  }
  zc[(b * 256 + c) * HW + pix] = acc;
  float S = wredsum(acc), Q = wredsum(acc * acc);
  __shared__ float l[8];
  int lane = tid & 63, wid = tid >> 6;
  if (lane == 0){ l[wid] = S; l[4 + wid] = Q; }
  __syncthreads();
  if (tid == 0){
    float SS = l[0] + l[1] + l[2] + l[3];
    float QQ = l[4] + l[5] + l[6] + l[7];
    int blkid = (b * 256 + c) * 25 + blockIdx.x;
    gnpart[blkid * 2] = SS; gnpart[blkid * 2 + 1] = QQ;
  }
}

// ---------------- K2: GN stats finalize -> per (b,c) scale/shift ----------------
__global__ __launch_bounds__(256) void k_gnfin(
    const float* __restrict__ gnpart, const float* __restrict__ gn_w,
    const float* __restrict__ gn_b, float* __restrict__ gn_sc){
  int tid = threadIdx.x; int bg = blockIdx.x; // b*4+g
  float S = 0.f, Q = 0.f;
  for (int i = tid; i < 1600; i += 256){
    S += gnpart[(bg * 1600 + i) * 2];
    Q += gnpart[(bg * 1600 + i) * 2 + 1];
  }
  S = wredsum(S); Q = wredsum(Q);
  __shared__ float l[8];
  int lane = tid & 63, wid = tid >> 6;
  if (lane == 0){ l[wid] = S; l[4 + wid] = Q; }
  __syncthreads();
  float SS = l[0] + l[1] + l[2] + l[3];
  float QQ = l[4] + l[5] + l[6] + l[7];
  float M = 64.f * HW;
  float mean = SS / M;
  float var = QQ / M - mean * mean;
  float rstd = rsqrtf(var + 1e-5f);
  if (tid < 64){
    int b = bg >> 2, g = bg & 3;
    int c = g * 64 + tid;
    float sc = gn_w[c] * rstd;
    float sh = gn_b[c] - mean * sc;
    gn_sc[(b * 256 + c) * 2] = sc;
    gn_sc[(b * 256 + c) * 2 + 1] = sh;
  }
}

// ---------------- K3: GN-apply + 1x1 conv (256->256) + bias + GELU ----------------
__global__ __launch_bounds__(256) void k_conv1(
    const float* __restrict__ zc, const float* __restrict__ gn_sc,
    const float* __restrict__ cw, const float* __restrict__ cb,
    float* __restrict__ zc2){
  int tid = threadIdx.x;
  int pix = blockIdx.x * 256 + tid;
  int ot = blockIdx.y * 32;
  int b = blockIdx.z;
  float acc[32];
  #pragma unroll
  for (int o = 0; o < 32; o++) acc[o] = 0.f;
  for (int c0 = 0; c0 < 256; c0 += 16){
    float xv[16];
    #pragma unroll
    for (int cc = 0; cc < 16; cc++){
      int c = c0 + cc;
      float sc = gn_sc[(b * 256 + c) * 2], sh = gn_sc[(b * 256 + c) * 2 + 1];
      xv[cc] = zc[(b * 256 + c) * HW + pix] * sc + sh;
    }
    #pragma unroll
    for (int o = 0; o < 32; o++){
      const float* wr = cw + (ot + o) * 256 + c0;
      float a = acc[o];
      #pragma unroll
      for (int cc = 0; cc < 16; cc++) a += wr[cc] * xv[cc];
      acc[o] = a;
    }
  }
  #pragma unroll
  for (int o = 0; o < 32; o++){
    float v = acc[o] + cb[ot + o];
    v = 0.5f * v * (1.f + erff(v * 0.70710678118f));
    zc2[(b * 256 + ot + o) * HW + pix] = v;
  }
}

// ---------------- K4a: 3x3 conv 256->32 (c5a|c5c fused), split-K partials ----------------
// grid (100, 8, 2), block 64: one pixel/thread, 32 input channels per block.
__global__ __launch_bounds__(64) void k_conv5ac_part(
    const float* __restrict__ zc2, const float* __restrict__ wa,
    const float* __restrict__ wc, float* __restrict__ partial){
  int tid = threadIdx.x;
  int pix = blockIdx.x * 64 + tid;
  int icc = blockIdx.y, b = blockIdx.z;
  int h = pix / 80, w = pix % 80;
  int off[9]; float msk[9];
  #pragma unroll
  for (int dy = 0; dy < 3; dy++){
    #pragma unroll
    for (int dx = 0; dx < 3; dx++){
      int hh = h + dy - 1, ww = w + dx - 1;
      bool ok = ((unsigned)hh < 80u) && ((unsigned)ww < 80u);
      off[dy * 3 + dx] = ok ? hh * 80 + ww : 0;
      msk[dy * 3 + dx] = ok ? 1.f : 0.f;
    }
  }
  float acc[32];
  #pragma unroll
  for (int o = 0; o < 32; o++) acc[o] = 0.f;
  int ic0 = icc * 32;
  const float* xbase = zc2 + (size_t)(b * 256 + ic0) * HW;
  for (int ic = 0; ic < 32; ic++){
    const float* xin = xbase + (size_t)ic * HW;
    float xv[9];
    #pragma unroll
    for (int k = 0; k < 9; k++) xv[k] = xin[off[k]] * msk[k];
    #pragma unroll
    for (int o = 0; o < 16; o++){
      const float* wra = wa + (o * 256 + ic0 + ic) * 9;   // uniform -> s_load
      const float* wrc = wc + (o * 256 + ic0 + ic) * 9;
      float a0 = acc[o], a1 = acc[16 + o];
      #pragma unroll
      for (int k = 0; k < 9; k++){ a0 += wra[k] * xv[k]; a1 += wrc[k] * xv[k]; }
      acc[o] = a0; acc[16 + o] = a1;
    }
  }
  float* pp = partial + ((size_t)(icc * 2 + b) * 32) * HW + pix;
  #pragma unroll
  for (int o = 0; o < 32; o++) pp[(size_t)o * HW] = acc[o];
}

// ---------------- K4b: reduce split-K partials -> fpre + BN partial stats ----------------
// grid (25, 32, 2), block 256
__global__ __launch_bounds__(256) void k_conv5ac_red(
    const float* __restrict__ partial, float* __restrict__ fpre,
    float* __restrict__ bnpart){
  int tid = threadIdx.x; int oc = blockIdx.y, b = blockIdx.z;
  int pix = blockIdx.x * 256 + tid;
  float s = 0.f;
  #pragma unroll
  for (int icc = 0; icc < 8; icc++)
    s += partial[((size_t)(icc * 2 + b) * 32 + oc) * HW + pix];
  fpre[(b * 32 + oc) * HW + pix] = s;
  float S = wredsum(s), Q = wredsum(s * s);
  __shared__ float l[8];
  int lane = tid & 63, wid = tid >> 6;
  if (lane == 0){ l[wid] = S; l[4 + wid] = Q; }
  __syncthreads();
  if (tid == 0){
    bnpart[oc * 100 + (b * 25 + blockIdx.x) * 2]     = l[0] + l[1] + l[2] + l[3];
    bnpart[oc * 100 + (b * 25 + blockIdx.x) * 2 + 1] = l[4] + l[5] + l[6] + l[7];
  }
}

// ---------------- K5/K12: BN finalize (32 channels) ----------------
// part layout: part[oc*(2*nent) + i*2 + j], i in [0,nent)
__global__ void k_bnfin(
    const float* __restrict__ part, int nent,
    const float* __restrict__ w1, const float* __restrict__ b1,
    const float* __restrict__ w2, const float* __restrict__ b2,
    float* __restrict__ sc_out){
  int oc = threadIdx.x; if (oc >= 32) return;
  float S = 0.f, Q = 0.f;
  for (int i = 0; i < nent; i++){
    S += part[oc * 2 * nent + i * 2];
    Q += part[oc * 2 * nent + i * 2 + 1];
  }
  float M = 2.f * HW;
  float mean = S / M, var = Q / M - mean * mean;
  float rstd = rsqrtf(var + 1e-3f);
  float w  = (oc < 16) ? w1[oc] : w2[oc - 16];
  float bb = (oc < 16) ? b1[oc] : b2[oc - 16];
  float sc = w * rstd, sh = bb - mean * sc;
  sc_out[oc * 2] = sc; sc_out[oc * 2 + 1] = sh;
}

// ---------------- K6: BN+relu apply -> feat1/feat2, and q,k,v 1x1 convs ----------------
__global__ __launch_bounds__(256) void k_featqkv(
    const float* __restrict__ fpre, const float* __restrict__ bnsc,
    const float* __restrict__ pqw, const float* __restrict__ pqb,
    const float* __restrict__ pkw, const float* __restrict__ pkb,
    const float* __restrict__ pvw, const float* __restrict__ pvb,
    float* __restrict__ feat, float* __restrict__ qkvT){
  int tid = threadIdx.x; int b = blockIdx.y;
  int n = blockIdx.x * 256 + tid;
  float f1[16], f2[16];
  #pragma unroll
  for (int c = 0; c < 16; c++){
    float v1 = fpre[(b * 32 + c) * HW + n] * bnsc[c * 2] + bnsc[c * 2 + 1];
    f1[c] = fmaxf(v1, 0.f);
    float v2 = fpre[(b * 32 + 16 + c) * HW + n] * bnsc[(16 + c) * 2] + bnsc[(16 + c) * 2 + 1];
    f2[c] = fmaxf(v2, 0.f);
    feat[(b * 32 + c) * HW + n] = f1[c];
    feat[(b * 32 + 16 + c) * HW + n] = f2[c];
  }
  float* o = qkvT + ((size_t)b * HW + n) * 20;
  #pragma unroll
  for (int j = 0; j < 2; j++){
    float q = pqb[j], k = pkb[j];
    #pragma unroll
    for (int c = 0; c < 16; c++){ q += pqw[j * 16 + c] * f1[c]; k += pkw[j * 16 + c] * f1[c]; }
    o[j] = q; o[2 + j] = k;
  }
  #pragma unroll
  for (int j = 0; j < 16; j++){
    float v = pvb[j];
    #pragma unroll
    for (int c = 0; c < 16; c++) v += pvw[j * 16 + c] * f1[c];
    o[4 + j] = v;
  }
}

// ---------------- K7a: PAM flash partials over m-chunks ----------------
__global__ __launch_bounds__(256) void k_pam_a(
    const float* __restrict__ qkvT, float* __restrict__ part){
  int tid = threadIdx.x;
  int n = blockIdx.x * 256 + tid;
  int mc = blockIdx.y, b = blockIdx.z;
  const float* qp = qkvT + ((size_t)b * HW + n) * 20;
  float q0 = qp[0], q1 = qp[1];
  float mx = -1e30f, Z = 0.f;
  float acc[16];
  #pragma unroll
  for (int c = 0; c < 16; c++) acc[c] = 0.f;
  const float* kvbase = qkvT + ((size_t)b * HW + mc * 800) * 20;
  for (int mi = 0; mi < 800; mi++){
    const float* kv = kvbase + mi * 20;          // uniform across block -> scalar loads
    float k0 = kv[2], k1 = kv[3];
    float s = q0 * k0 + q1 * k1;
    if (s <= mx){
      float p = __expf(s - mx);
      Z += p;
      #pragma unroll
      for (int c = 0; c < 16; c++) acc[c] += p * kv[4 + c];
    } else {
      float r = __expf(mx - s);
      mx = s;
      Z = Z * r + 1.f;
      #pragma unroll
      for (int c = 0; c < 16; c++) acc[c] = acc[c] * r + kv[4 + c];
    }
  }
  float* pp = part + ((size_t)(b * 8 + mc) * 18) * HW + n;
  pp[0] = mx; pp[HW] = Z;
  #pragma unroll
  for (int c = 0; c < 16; c++) pp[(size_t)(2 + c) * HW] = acc[c];
}

// ---------------- K7b: merge PAM partials, residual ----------------
__global__ __launch_bounds__(256) void k_pam_b(
    const float* __restrict__ part, const float* __restrict__ feat,
    const float* __restrict__ gammap, float* __restrict__ pam_in){
  int tid = threadIdx.x; int b = blockIdx.y;
  int n = blockIdx.x * 256 + tid;
  float gamma = gammap[0];
  float mxs[8]; float mx = -1e30f;
  #pragma unroll
  for (int mc = 0; mc < 8; mc++){
    mxs[mc] = part[((size_t)(b * 8 + mc) * 18) * HW + n];
    mx = fmaxf(mx, mxs[mc]);
  }
  float Z = 0.f, acc[16];
  #pragma unroll
  for (int c = 0; c < 16; c++) acc[c] = 0.f;
  #pragma unroll
  for (int mc = 0; mc < 8; mc++){
    const float* pp = part + ((size_t)(b * 8 + mc) * 18) * HW + n;
    float r = __expf(mxs[mc] - mx);
    Z += pp[HW] * r;
    #pragma unroll
    for (int c = 0; c < 16; c++) acc[c] += pp[(size_t)(2 + c) * HW] * r;
  }
  float inv = 1.f / Z;
  #pragma unroll
  for (int c = 0; c < 16; c++){
    float pa = acc[c] * inv;
    pam_in[(b * 16 + c) * HW + n] = gamma * pa + feat[(b * 32 + c) * HW + n];
  }
}

// ---------------- K8: CAM gram matrix e[b,c,d] ----------------
__global__ __launch_bounds__(256) void k_cam_gram(
    const float* __restrict__ feat, float* __restrict__ e){
  int tid = threadIdx.x;
  int dd = blockIdx.x, c = blockIdx.y, b = blockIdx.z;
  const float* fc = feat + (b * 32 + 16 + c) * HW;
  const float* fd = feat + (b * 32 + 16 + dd) * HW;
  float S = 0.f;
  for (int i = tid; i < HW; i += 256) S += fc[i] * fd[i];
  S = wredsum(S);
  __shared__ float l[4];
  int lane = tid & 63, wid = tid >> 6;
  if (lane == 0) l[wid] = S;
  __syncthreads();
  if (tid == 0) e[(b * 16 + c) * 16 + dd] = l[0] + l[1] + l[2] + l[3];
}

// ---------------- K9: CAM softmax of (max - e) rows ----------------
__global__ void k_cam_soft(const float* __restrict__ e, float* __restrict__ att){
  int tid = threadIdx.x; if (tid >= 32) return;
  int b = tid >> 4, c = tid & 15;
  const float* row = e + (b * 16 + c) * 16;
  float r[16]; float mn = 1e30f;
  #pragma unroll
  for (int d = 0; d < 16; d++){ r[d] = row[d]; mn = fminf(mn, r[d]); }
  float p[16]; float s = 0.f;
  #pragma unroll
  for (int d = 0; d < 16; d++){ p[d] = __expf(mn - r[d]); s += p[d]; }
  float inv = 1.f / s;
  #pragma unroll
  for (int d = 0; d < 16; d++) att[(b * 16 + c) * 16 + d] = p[d] * inv;
}

// ---------------- K10: CAM apply + residual ----------------
__global__ __launch_bounds__(256) void k_cam_apply(
    const float* __restrict__ att, const float* __restrict__ feat,
    const float* __restrict__ gammap, float* __restrict__ cam_in){
  int tid = threadIdx.x; int c = blockIdx.y, b = blockIdx.z;
  int n = blockIdx.x * 256 + tid;
  const float* arow = att + (b * 16 + c) * 16;
  float s = 0.f;
  #pragma unroll
  for (int d = 0; d < 16; d++) s += arow[d] * feat[(b * 32 + 16 + d) * HW + n];
  cam_in[(b * 16 + c) * HW + n] = gammap[0] * s + feat[(b * 32 + 16 + c) * HW + n];
}

// ---------------- K11: 3x3 conv 16->32 (c5b on pam | c5d on cam) + BN stats ----------------
// grid (100, 2, 2), block 64: one pixel/thread
__global__ __launch_bounds__(64) void k_conv5bd2(
    const float* __restrict__ pam_in, const float* __restrict__ cam_in,
    const float* __restrict__ wb, const float* __restrict__ wd,
    float* __restrict__ bdpre, float* __restrict__ bnpart){
  int tid = threadIdx.x;
  int pix = blockIdx.x * 64 + tid;
  int half = blockIdx.y, b = blockIdx.z;
  int h = pix / 80, w = pix % 80;
  int off[9]; float msk[9];
  #pragma unroll
  for (int dy = 0; dy < 3; dy++){
    #pragma unroll
    for (int dx = 0; dx < 3; dx++){
      int hh = h + dy - 1, ww = w + dx - 1;
      bool ok = ((unsigned)hh < 80u) && ((unsigned)ww < 80u);
      off[dy * 3 + dx] = ok ? hh * 80 + ww : 0;
      msk[dy * 3 + dx] = ok ? 1.f : 0.f;
    }
  }
  const float* in = (half ? cam_in : pam_in) + (size_t)b * 16 * HW;
  const float* wsel = half ? wd : wb;
  float acc[16];
  #pragma unroll
  for (int o = 0; o < 16; o++) acc[o] = 0.f;
  #pragma unroll
  for (int ic = 0; ic < 16; ic++){
    const float* xin = in + (size_t)ic * HW;
    float xv[9];
    #pragma unroll
    for (int k = 0; k < 9; k++) xv[k] = xin[off[k]] * msk[k];
    #pragma unroll
    for (int o = 0; o < 16; o++){
      const float* wr = wsel + (o * 16 + ic) * 9;   // uniform -> s_load
      float a = acc[o];
      #pragma unroll
      for (int k = 0; k < 9; k++) a += wr[k] * xv[k];
      acc[o] = a;
    }
  }
  int oc0 = half * 16;
  #pragma unroll
  for (int o = 0; o < 16; o++){
    float v = acc[o];
    bdpre[(b * 32 + oc0 + o) * HW + pix] = v;
    float S = wredsum(v), Q = wredsum(v * v);
    if (tid == 0){
      bnpart[(oc0 + o) * 400 + (b * 100 + blockIdx.x) * 2]     = S;
      bnpart[(oc0 + o) * 400 + (b * 100 + blockIdx.x) * 2 + 1] = Q;
    }
  }
}

// ---------------- K13: BN+relu both halves, sum ----------------
__global__ __launch_bounds__(256) void k_ssum(
    const float* __restrict__ bdpre, const float* __restrict__ bnsc,
    float* __restrict__ ssum){
  int tid = threadIdx.x; int c = blockIdx.y, b = blockIdx.z;
  int n = blockIdx.x * 256 + tid;
  float v1 = bdpre[(b * 32 + c) * HW + n] * bnsc[c * 2] + bnsc[c * 2 + 1];
  float v2 = bdpre[(b * 32 + 16 + c) * HW + n] * bnsc[(16 + c) * 2] + bnsc[(16 + c) * 2 + 1];
  ssum[(b * 16 + c) * HW + n] = fmaxf(v1, 0.f) + fmaxf(v2, 0.f);
}

// ---------------- K14: 1x1 conv 16->256 + bias + relu -> out ----------------
__global__ __launch_bounds__(256) void k_c6(
    const float* __restrict__ ssum, const float* __restrict__ w6,
    const float* __restrict__ b6, float* __restrict__ out){
  int tid = threadIdx.x; int og = blockIdx.y * 4, b = blockIdx.z;
  int n = blockIdx.x * 256 + tid;
  float x[16];
  #pragma unroll
  for (int c = 0; c < 16; c++) x[c] = ssum[(b * 16 + c) * HW + n];
  #pragma unroll
  for (int o = 0; o < 4; o++){
    float a = b6[og + o];
    #pragma unroll
    for (int c = 0; c < 16; c++) a += w6[(og + o) * 16 + c] * x[c];
    out[(b * 256 + og + o) * HW + n] = fmaxf(a, 0.f);
  }
}

extern "C" void kernel_launch(void* const* d_in, const int* in_sizes, int n_in,
                              void* d_out, int out_size, void* d_ws, size_t ws_size,
                              hipStream_t stream){
  const float* z      = (const float*)d_in[0];
  const float* w_at0  = (const float*)d_in[1];
  const float* b_at0  = (const float*)d_in[2];
  const float* w_at1  = (const float*)d_in[3];
  const float* b_at1  = (const float*)d_in[4];
  const float* w_at2  = (const float*)d_in[5];
  const float* b_at2  = (const float*)d_in[6];
  const float* w_at3  = (const float*)d_in[7];
  const float* b_at3  = (const float*)d_in[8];
  const float* gn_w   = (const float*)d_in[9];
  const float* gn_b   = (const float*)d_in[10];
  const float* conv_w = (const float*)d_in[11];
  const float* conv_b = (const float*)d_in[12];
  const float* c5a_w  = (const float*)d_in[13];
  const float* bn5a_w = (const float*)d_in[14];
  const float* bn5a_b = (const float*)d_in[15];
  const float* c5c_w  = (const float*)d_in[16];
  const float* bn5c_w = (const float*)d_in[17];
  const float* bn5c_b = (const float*)d_in[18];
  const float* pq_w   = (const float*)d_in[19];
  const float* pq_b   = (const float*)d_in[20];
  const float* pk_w   = (const float*)d_in[21];
  const float* pk_b   = (const float*)d_in[22];
  const float* pv_w   = (const float*)d_in[23];
  const float* pv_b   = (const float*)d_in[24];
  const float* pa_g   = (const float*)d_in[25];
  const float* ca_g   = (const float*)d_in[26];
  const float* c5b_w  = (const float*)d_in[27];
  const float* bn5b_w = (const float*)d_in[28];
  const float* bn5b_b = (const float*)d_in[29];
  const float* c5d_w  = (const float*)d_in[30];
  const float* bn5d_w = (const float*)d_in[31];
  const float* bn5d_b = (const float*)d_in[32];
  const float* c6_w   = (const float*)d_in[33];
  const float* c6_b   = (const float*)d_in[34];

  float* ws = (float*)d_ws;
  float* ZC      = ws;                    // 3,276,800 (aliased later as PARTIAL/PART)
  float* ZC2     = ZC + 3276800;          // 3,276,800
  float* FPRE    = ZC2 + 3276800;         // 409,600
  float* FEAT    = FPRE + 409600;         // 409,600
  float* QKVT    = FEAT + 409600;         // 256,000
  float* PAM_IN  = QKVT + 256000;         // 204,800
  float* CAM_IN  = PAM_IN + 204800;       // 204,800
  float* BDPRE   = CAM_IN + 204800;       // 409,600
  float* SSUM    = BDPRE + 409600;        // 204,800
  float* ST      = SSUM + 204800;
  float* GN_SC    = ST;                   // 1024
  float* BNA_SC   = ST + 1024;            // 64
  float* BNB_SC   = ST + 1088;            // 64
  float* CAM_ATT  = ST + 1152;            // 512
  float* CAM_E    = ST + 1664;            // 512
  float* GN_PART  = ST + 2176;            // 25,600
  float* BNA_PART = ST + 27776;           // 3,200
  float* BNB_PART = ST + 30976;           // 12,800 (32 oc * 400)
  // ZC is dead after k_conv1; conv5ac split-K partials (3,276,800 floats) alias it,
  // and are dead before k_pam_a writes PART into the same space.
  float* PARTIAL = ZC;
  float* PART    = ZC;

  k_dw<<<dim3(25, 256, 2), 256, 0, stream>>>(z, w_at0, b_at0, w_at1, b_at1,
                                             w_at2, b_at2, w_at3, b_at3, ZC, GN_PART);
  k_gnfin<<<8, 256, 0, stream>>>(GN_PART, gn_w, gn_b, GN_SC);
  k_conv1<<<dim3(25, 8, 2), 256, 0, stream>>>(ZC, GN_SC, conv_w, conv_b, ZC2);
  k_conv5ac_part<<<dim3(100, 8, 2), 64, 0, stream>>>(ZC2, c5a_w, c5c_w, PARTIAL);
  k_conv5ac_red<<<dim3(25, 32, 2), 256, 0, stream>>>(PARTIAL, FPRE, BNA_PART);
  k_bnfin<<<1, 32, 0, stream>>>(BNA_PART, 50, bn5a_w, bn5a_b, bn5c_w, bn5c_b, BNA_SC);
  k_featqkv<<<dim3(25, 2), 256, 0, stream>>>(FPRE, BNA_SC, pq_w, pq_b, pk_w, pk_b,
                                             pv_w, pv_b, FEAT, QKVT);
  k_pam_a<<<dim3(25, 8, 2), 256, 0, stream>>>(QKVT, PART);
  k_pam_b<<<dim3(25, 2), 256, 0, stream>>>(PART, FEAT, pa_g, PAM_IN);
  k_cam_gram<<<dim3(16, 16, 2), 256, 0, stream>>>(FEAT, CAM_E);
  k_cam_soft<<<1, 64, 0, stream>>>(CAM_E, CAM_ATT);
  k_cam_apply<<<dim3(25, 16, 2), 256, 0, stream>>>(CAM_ATT, FEAT, ca_g, CAM_IN);
  k_conv5bd2<<<dim3(100, 2, 2), 64, 0, stream>>>(PAM_IN, CAM_IN, c5b_w, c5d_w, BDPRE, BNB_PART);
  k_bnfin<<<1, 32, 0, stream>>>(BNB_PART, 200, bn5b_w, bn5b_b, bn5d_w, bn5d_b, BNB_SC);
  k_ssum<<<dim3(25, 16, 2), 256, 0, stream>>>(BDPRE, BNB_SC, SSUM);
  k_c6<<<dim3(25, 64, 2), 256, 0, stream>>>(SSUM, c6_w, c6_b, (float*)d_out);
}

// Round 3
// 414.309 us; speedup vs baseline: 2.0147x; 1.4622x over previous
//
#include <hip/hip_runtime.h>
#include <math.h>

#define HW 6400

__device__ __forceinline__ float wredsum(float v){
  #pragma unroll
  for (int o = 32; o; o >>= 1) v += __shfl_xor(v, o);
  return v;
}

// ---------------- K1: depthwise dilated convs + GN partial stats ----------------
__global__ __launch_bounds__(256) void k_dw(
    const float* __restrict__ z,
    const float* __restrict__ w0, const float* __restrict__ b0,
    const float* __restrict__ w1, const float* __restrict__ b1,
    const float* __restrict__ w2, const float* __restrict__ b2,
    const float* __restrict__ w3, const float* __restrict__ b3,
    float* __restrict__ zc, float* __restrict__ gnpart){
  int tid = threadIdx.x;
  int c = blockIdx.y, b = blockIdx.z;
  int pix = blockIdx.x * 256 + tid;
  int h = pix / 80, w = pix % 80;
  int part = c >> 6, cl = c & 63;
  const float* wp; const float* bp; int d;
  if (part == 0)      { wp = w0; bp = b0; d = 7; }
  else if (part == 1) { wp = w1; bp = b1; d = 5; }
  else if (part == 2) { wp = w2; bp = b2; d = 2; }
  else                { wp = w3; bp = b3; d = 1; }
  wp += cl * 9;
  const float* zin = z + (b * 256 + c) * HW;
  float acc = bp[cl];
  #pragma unroll
  for (int kh = 0; kh < 3; kh++){
    int hh = h + (kh - 1) * d;
    if ((unsigned)hh < 80u){
      #pragma unroll
      for (int kw = 0; kw < 3; kw++){
        int ww = w + (kw - 1) * d;
        if ((unsigned)ww < 80u) acc += wp[kh * 3 + kw] * zin[hh * 80 + ww];
      }
    }
  }
  zc[(b * 256 + c) * HW + pix] = acc;
  float S = wredsum(acc), Q = wredsum(acc * acc);
  __shared__ float l[8];
  int lane = tid & 63, wid = tid >> 6;
  if (lane == 0){ l[wid] = S; l[4 + wid] = Q; }
  __syncthreads();
  if (tid == 0){
    float SS = l[0] + l[1] + l[2] + l[3];
    float QQ = l[4] + l[5] + l[6] + l[7];
    int blkid = (b * 256 + c) * 25 + blockIdx.x;
    gnpart[blkid * 2] = SS; gnpart[blkid * 2 + 1] = QQ;
  }
}

// ---------------- K2: GN stats finalize -> per (b,c) scale/shift ----------------
__global__ __launch_bounds__(256) void k_gnfin(
    const float* __restrict__ gnpart, const float* __restrict__ gn_w,
    const float* __restrict__ gn_b, float* __restrict__ gn_sc){
  int tid = threadIdx.x; int bg = blockIdx.x; // b*4+g
  float S = 0.f, Q = 0.f;
  for (int i = tid; i < 1600; i += 256){
    S += gnpart[(bg * 1600 + i) * 2];
    Q += gnpart[(bg * 1600 + i) * 2 + 1];
  }
  S = wredsum(S); Q = wredsum(Q);
  __shared__ float l[8];
  int lane = tid & 63, wid = tid >> 6;
  if (lane == 0){ l[wid] = S; l[4 + wid] = Q; }
  __syncthreads();
  float SS = l[0] + l[1] + l[2] + l[3];
  float QQ = l[4] + l[5] + l[6] + l[7];
  float M = 64.f * HW;
  float mean = SS / M;
  float var = QQ / M - mean * mean;
  float rstd = rsqrtf(var + 1e-5f);
  if (tid < 64){
    int b = bg >> 2, g = bg & 3;
    int c = g * 64 + tid;
    float sc = gn_w[c] * rstd;
    float sh = gn_b[c] - mean * sc;
    gn_sc[(b * 256 + c) * 2] = sc;
    gn_sc[(b * 256 + c) * 2 + 1] = sh;
  }
}

// ---------------- K3: GN-apply + 1x1 conv (256->256) + bias + GELU ----------------
// grid (25, 16, 2), block 256: 16 outputs/thread, ping-pong channel prefetch
__global__ __launch_bounds__(256) void k_conv1(
    const float* __restrict__ zc, const float* __restrict__ gn_sc,
    const float* __restrict__ cw, const float* __restrict__ cb,
    float* __restrict__ zc2){
  int tid = threadIdx.x;
  int pix = blockIdx.x * 256 + tid;
  int ot = blockIdx.y * 16;
  int b = blockIdx.z;
  const float* zbase = zc + (size_t)b * 256 * HW + pix;
  const float* gbase = gn_sc + b * 512;
  float acc[16];
  #pragma unroll
  for (int o = 0; o < 16; o++) acc[o] = 0.f;
  float xa[16], xb[16];
  #pragma unroll
  for (int cc = 0; cc < 16; cc++)
    xa[cc] = zbase[(size_t)cc * HW] * gbase[cc * 2] + gbase[cc * 2 + 1];
  for (int c0 = 0; c0 < 256; c0 += 32){
    // prefetch next 16 channels
    #pragma unroll
    for (int cc = 0; cc < 16; cc++){
      int c = c0 + 16 + cc;
      xb[cc] = zbase[(size_t)c * HW] * gbase[c * 2] + gbase[c * 2 + 1];
    }
    #pragma unroll
    for (int o = 0; o < 16; o++){
      const float* wr = cw + (ot + o) * 256 + c0;
      float a = acc[o];
      #pragma unroll
      for (int cc = 0; cc < 16; cc++) a += wr[cc] * xa[cc];
      acc[o] = a;
    }
    if (c0 + 32 < 256){
      #pragma unroll
      for (int cc = 0; cc < 16; cc++){
        int c = c0 + 32 + cc;
        xa[cc] = zbase[(size_t)c * HW] * gbase[c * 2] + gbase[c * 2 + 1];
      }
    }
    #pragma unroll
    for (int o = 0; o < 16; o++){
      const float* wr = cw + (ot + o) * 256 + c0 + 16;
      float a = acc[o];
      #pragma unroll
      for (int cc = 0; cc < 16; cc++) a += wr[cc] * xb[cc];
      acc[o] = a;
    }
  }
  #pragma unroll
  for (int o = 0; o < 16; o++){
    float v = acc[o] + cb[ot + o];
    v = 0.5f * v * (1.f + erff(v * 0.70710678118f));
    zc2[(b * 256 + ot + o) * HW + pix] = v;
  }
}

// ---------------- K4a: 3x3 conv 256->32 (c5a|c5c fused), split-K partials ----------------
// grid (100, 8, 2), block 64: one pixel/thread, 32 input channels per block.
__global__ __launch_bounds__(64) void k_conv5ac_part(
    const float* __restrict__ zc2, const float* __restrict__ wa,
    const float* __restrict__ wc, float* __restrict__ partial){
  int tid = threadIdx.x;
  int pix = blockIdx.x * 64 + tid;
  int icc = blockIdx.y, b = blockIdx.z;
  int h = pix / 80, w = pix % 80;
  int off[9]; float msk[9];
  #pragma unroll
  for (int dy = 0; dy < 3; dy++){
    #pragma unroll
    for (int dx = 0; dx < 3; dx++){
      int hh = h + dy - 1, ww = w + dx - 1;
      bool ok = ((unsigned)hh < 80u) && ((unsigned)ww < 80u);
      off[dy * 3 + dx] = ok ? hh * 80 + ww : 0;
      msk[dy * 3 + dx] = ok ? 1.f : 0.f;
    }
  }
  float acc[32];
  #pragma unroll
  for (int o = 0; o < 32; o++) acc[o] = 0.f;
  int ic0 = icc * 32;
  const float* xbase = zc2 + (size_t)(b * 256 + ic0) * HW;
  float xa[9], xb[9];
  #pragma unroll
  for (int k = 0; k < 9; k++) xa[k] = xbase[off[k]] * msk[k];
  for (int ic = 0; ic < 32; ic += 2){
    const float* xin1 = xbase + (size_t)(ic + 1) * HW;
    #pragma unroll
    for (int k = 0; k < 9; k++) xb[k] = xin1[off[k]] * msk[k];
    #pragma unroll
    for (int o = 0; o < 16; o++){
      const float* wra = wa + (o * 256 + ic0 + ic) * 9;
      const float* wrc = wc + (o * 256 + ic0 + ic) * 9;
      float a0 = acc[o], a1 = acc[16 + o];
      #pragma unroll
      for (int k = 0; k < 9; k++){ a0 += wra[k] * xa[k]; a1 += wrc[k] * xa[k]; }
      acc[o] = a0; acc[16 + o] = a1;
    }
    if (ic + 2 < 32){
      const float* xin2 = xbase + (size_t)(ic + 2) * HW;
      #pragma unroll
      for (int k = 0; k < 9; k++) xa[k] = xin2[off[k]] * msk[k];
    }
    #pragma unroll
    for (int o = 0; o < 16; o++){
      const float* wra = wa + (o * 256 + ic0 + ic + 1) * 9;
      const float* wrc = wc + (o * 256 + ic0 + ic + 1) * 9;
      float a0 = acc[o], a1 = acc[16 + o];
      #pragma unroll
      for (int k = 0; k < 9; k++){ a0 += wra[k] * xb[k]; a1 += wrc[k] * xb[k]; }
      acc[o] = a0; acc[16 + o] = a1;
    }
  }
  float* pp = partial + ((size_t)(icc * 2 + b) * 32) * HW + pix;
  #pragma unroll
  for (int o = 0; o < 32; o++) pp[(size_t)o * HW] = acc[o];
}

// ---------------- K4b: reduce split-K partials -> fpre + BN partial stats ----------------
__global__ __launch_bounds__(256) void k_conv5ac_red(
    const float* __restrict__ partial, float* __restrict__ fpre,
    float* __restrict__ bnpart){
  int tid = threadIdx.x; int oc = blockIdx.y, b = blockIdx.z;
  int pix = blockIdx.x * 256 + tid;
  float s = 0.f;
  #pragma unroll
  for (int icc = 0; icc < 8; icc++)
    s += partial[((size_t)(icc * 2 + b) * 32 + oc) * HW + pix];
  fpre[(b * 32 + oc) * HW + pix] = s;
  float S = wredsum(s), Q = wredsum(s * s);
  __shared__ float l[8];
  int lane = tid & 63, wid = tid >> 6;
  if (lane == 0){ l[wid] = S; l[4 + wid] = Q; }
  __syncthreads();
  if (tid == 0){
    bnpart[oc * 100 + (b * 25 + blockIdx.x) * 2]     = l[0] + l[1] + l[2] + l[3];
    bnpart[oc * 100 + (b * 25 + blockIdx.x) * 2 + 1] = l[4] + l[5] + l[6] + l[7];
  }
}

// ---------------- K5/K12: BN finalize (32 channels), parallel reduce ----------------
__global__ __launch_bounds__(256) void k_bnfin(
    const float* __restrict__ part, int nent,
    const float* __restrict__ w1, const float* __restrict__ b1,
    const float* __restrict__ w2, const float* __restrict__ b2,
    float* __restrict__ sc_out){
  __shared__ float lS[8][32], lQ[8][32];
  int tid = threadIdx.x;
  int oc = tid & 31, sl = tid >> 5;
  float S = 0.f, Q = 0.f;
  for (int i = sl; i < nent; i += 8){
    S += part[oc * 2 * nent + i * 2];
    Q += part[oc * 2 * nent + i * 2 + 1];
  }
  lS[sl][oc] = S; lQ[sl][oc] = Q;
  __syncthreads();
  if (tid < 32){
    float SS = 0.f, QQ = 0.f;
    #pragma unroll
    for (int s = 0; s < 8; s++){ SS += lS[s][oc]; QQ += lQ[s][oc]; }
    float M = 2.f * HW;
    float mean = SS / M, var = QQ / M - mean * mean;
    float rstd = rsqrtf(var + 1e-3f);
    float w  = (oc < 16) ? w1[oc] : w2[oc - 16];
    float bb = (oc < 16) ? b1[oc] : b2[oc - 16];
    float sc = w * rstd, sh = bb - mean * sc;
    sc_out[oc * 2] = sc; sc_out[oc * 2 + 1] = sh;
  }
}

// ---------------- K6: BN+relu apply -> feat1/feat2, and q,k,v 1x1 convs ----------------
__global__ __launch_bounds__(256) void k_featqkv(
    const float* __restrict__ fpre, const float* __restrict__ bnsc,
    const float* __restrict__ pqw, const float* __restrict__ pqb,
    const float* __restrict__ pkw, const float* __restrict__ pkb,
    const float* __restrict__ pvw, const float* __restrict__ pvb,
    float* __restrict__ feat, float* __restrict__ qkvT){
  int tid = threadIdx.x; int b = blockIdx.y;
  int n = blockIdx.x * 256 + tid;
  float f1[16], f2[16];
  #pragma unroll
  for (int c = 0; c < 16; c++){
    float v1 = fpre[(b * 32 + c) * HW + n] * bnsc[c * 2] + bnsc[c * 2 + 1];
    f1[c] = fmaxf(v1, 0.f);
    float v2 = fpre[(b * 32 + 16 + c) * HW + n] * bnsc[(16 + c) * 2] + bnsc[(16 + c) * 2 + 1];
    f2[c] = fmaxf(v2, 0.f);
    feat[(b * 32 + c) * HW + n] = f1[c];
    feat[(b * 32 + 16 + c) * HW + n] = f2[c];
  }
  float* o = qkvT + ((size_t)b * HW + n) * 20;
  #pragma unroll
  for (int j = 0; j < 2; j++){
    float q = pqb[j], k = pkb[j];
    #pragma unroll
    for (int c = 0; c < 16; c++){ q += pqw[j * 16 + c] * f1[c]; k += pkw[j * 16 + c] * f1[c]; }
    o[j] = q; o[2 + j] = k;
  }
  #pragma unroll
  for (int j = 0; j < 16; j++){
    float v = pvb[j];
    #pragma unroll
    for (int c = 0; c < 16; c++) v += pvw[j * 16 + c] * f1[c];
    o[4 + j] = v;
  }
}

// ---------------- K7a: PAM flash partials, 16 m-chunks, deferred-max ----------------
__global__ __launch_bounds__(256) void k_pam_a(
    const float* __restrict__ qkvT, float* __restrict__ part){
  int tid = threadIdx.x;
  int n = blockIdx.x * 256 + tid;
  int mc = blockIdx.y, b = blockIdx.z;
  const float* qp = qkvT + ((size_t)b * HW + n) * 20;
  float q0 = qp[0], q1 = qp[1];
  float mx = -1e30f, Z = 0.f;
  float acc[16];
  #pragma unroll
  for (int c = 0; c < 16; c++) acc[c] = 0.f;
  const float* kvbase = qkvT + ((size_t)b * HW + mc * 400) * 20;
  #pragma unroll 2
  for (int mi = 0; mi < 400; mi++){
    const float* kv = kvbase + mi * 20;          // uniform across block -> scalar loads
    float k0 = kv[2], k1 = kv[3];
    float s = q0 * k0 + q1 * k1;
    if (__any(s > mx + 8.f)){                    // rare after warm-up
      float nmx = fmaxf(mx, s);
      float r = __expf(mx - nmx);
      mx = nmx;
      Z *= r;
      #pragma unroll
      for (int c = 0; c < 16; c++) acc[c] *= r;
    }
    float p = __expf(s - mx);                    // bounded by e^8
    Z += p;
    #pragma unroll
    for (int c = 0; c < 16; c++) acc[c] += p * kv[4 + c];
  }
  float* pp = part + ((size_t)(b * 16 + mc) * 18) * HW + n;
  pp[0] = mx; pp[HW] = Z;
  #pragma unroll
  for (int c = 0; c < 16; c++) pp[(size_t)(2 + c) * HW] = acc[c];
}

// ---------------- K7b: merge PAM partials, residual ----------------
__global__ __launch_bounds__(256) void k_pam_b(
    const float* __restrict__ part, const float* __restrict__ feat,
    const float* __restrict__ gammap, float* __restrict__ pam_in){
  int tid = threadIdx.x; int b = blockIdx.y;
  int n = blockIdx.x * 256 + tid;
  float gamma = gammap[0];
  float mxs[16]; float mx = -1e30f;
  #pragma unroll
  for (int mc = 0; mc < 16; mc++){
    mxs[mc] = part[((size_t)(b * 16 + mc) * 18) * HW + n];
    mx = fmaxf(mx, mxs[mc]);
  }
  float Z = 0.f, acc[16];
  #pragma unroll
  for (int c = 0; c < 16; c++) acc[c] = 0.f;
  #pragma unroll
  for (int mc = 0; mc < 16; mc++){
    const float* pp = part + ((size_t)(b * 16 + mc) * 18) * HW + n;
    float r = __expf(mxs[mc] - mx);
    Z += pp[HW] * r;
    #pragma unroll
    for (int c = 0; c < 16; c++) acc[c] += pp[(size_t)(2 + c) * HW] * r;
  }
  float inv = 1.f / Z;
  #pragma unroll
  for (int c = 0; c < 16; c++){
    float pa = acc[c] * inv;
    pam_in[(b * 16 + c) * HW + n] = gamma * pa + feat[(b * 32 + c) * HW + n];
  }
}

// ---------------- K8: CAM gram matrix e[b,c,d] ----------------
__global__ __launch_bounds__(256) void k_cam_gram(
    const float* __restrict__ feat, float* __restrict__ e){
  int tid = threadIdx.x;
  int dd = blockIdx.x, c = blockIdx.y, b = blockIdx.z;
  const float* fc = feat + (b * 32 + 16 + c) * HW;
  const float* fd = feat + (b * 32 + 16 + dd) * HW;
  float S = 0.f;
  for (int i = tid; i < HW; i += 256) S += fc[i] * fd[i];
  S = wredsum(S);
  __shared__ float l[4];
  int lane = tid & 63, wid = tid >> 6;
  if (lane == 0) l[wid] = S;
  __syncthreads();
  if (tid == 0) e[(b * 16 + c) * 16 + dd] = l[0] + l[1] + l[2] + l[3];
}

// ---------------- K9: CAM softmax of (max - e) rows ----------------
__global__ void k_cam_soft(const float* __restrict__ e, float* __restrict__ att){
  int tid = threadIdx.x; if (tid >= 32) return;
  int b = tid >> 4, c = tid & 15;
  const float* row = e + (b * 16 + c) * 16;
  float r[16]; float mn = 1e30f;
  #pragma unroll
  for (int d = 0; d < 16; d++){ r[d] = row[d]; mn = fminf(mn, r[d]); }
  float p[16]; float s = 0.f;
  #pragma unroll
  for (int d = 0; d < 16; d++){ p[d] = __expf(mn - r[d]); s += p[d]; }
  float inv = 1.f / s;
  #pragma unroll
  for (int d = 0; d < 16; d++) att[(b * 16 + c) * 16 + d] = p[d] * inv;
}

// ---------------- K10: CAM apply + residual ----------------
__global__ __launch_bounds__(256) void k_cam_apply(
    const float* __restrict__ att, const float* __restrict__ feat,
    const float* __restrict__ gammap, float* __restrict__ cam_in){
  int tid = threadIdx.x; int c = blockIdx.y, b = blockIdx.z;
  int n = blockIdx.x * 256 + tid;
  const float* arow = att + (b * 16 + c) * 16;
  float s = 0.f;
  #pragma unroll
  for (int d = 0; d < 16; d++) s += arow[d] * feat[(b * 32 + 16 + d) * HW + n];
  cam_in[(b * 16 + c) * HW + n] = gammap[0] * s + feat[(b * 32 + 16 + c) * HW + n];
}

// ---------------- K11: 3x3 conv 16->32 (c5b|c5d), 4 outputs/thread + BN stats ----------------
// grid (100, 8, 2), block 64
__global__ __launch_bounds__(64) void k_conv5bd2(
    const float* __restrict__ pam_in, const float* __restrict__ cam_in,
    const float* __restrict__ wb, const float* __restrict__ wd,
    float* __restrict__ bdpre, float* __restrict__ bnpart){
  int tid = threadIdx.x;
  int pix = blockIdx.x * 64 + tid;
  int ocg = blockIdx.y, b = blockIdx.z;
  int half = ocg >> 2, oq = (ocg & 3) * 4;
  int h = pix / 80, w = pix % 80;
  int off[9]; float msk[9];
  #pragma unroll
  for (int dy = 0; dy < 3; dy++){
    #pragma unroll
    for (int dx = 0; dx < 3; dx++){
      int hh = h + dy - 1, ww = w + dx - 1;
      bool ok = ((unsigned)hh < 80u) && ((unsigned)ww < 80u);
      off[dy * 3 + dx] = ok ? hh * 80 + ww : 0;
      msk[dy * 3 + dx] = ok ? 1.f : 0.f;
    }
  }
  const float* in = (half ? cam_in : pam_in) + (size_t)b * 16 * HW;
  const float* wsel = (half ? wd : wb) + oq * 16 * 9;
  float acc[4];
  #pragma unroll
  for (int o = 0; o < 4; o++) acc[o] = 0.f;
  float xa[9], xb[9];
  #pragma unroll
  for (int k = 0; k < 9; k++) xa[k] = in[off[k]] * msk[k];
  #pragma unroll
  for (int ic = 0; ic < 16; ic += 2){
    const float* xin1 = in + (size_t)(ic + 1) * HW;
    #pragma unroll
    for (int k = 0; k < 9; k++) xb[k] = xin1[off[k]] * msk[k];
    #pragma unroll
    for (int o = 0; o < 4; o++){
      const float* wr = wsel + (o * 16 + ic) * 9;
      float a = acc[o];
      #pragma unroll
      for (int k = 0; k < 9; k++) a += wr[k] * xa[k];
      acc[o] = a;
    }
    if (ic + 2 < 16){
      const float* xin2 = in + (size_t)(ic + 2) * HW;
      #pragma unroll
      for (int k = 0; k < 9; k++) xa[k] = xin2[off[k]] * msk[k];
    }
    #pragma unroll
    for (int o = 0; o < 4; o++){
      const float* wr = wsel + (o * 16 + ic + 1) * 9;
      float a = acc[o];
      #pragma unroll
      for (int k = 0; k < 9; k++) a += wr[k] * xb[k];
      acc[o] = a;
    }
  }
  int oc0 = half * 16 + oq;
  #pragma unroll
  for (int o = 0; o < 4; o++){
    float v = acc[o];
    bdpre[(b * 32 + oc0 + o) * HW + pix] = v;
    float S = wredsum(v), Q = wredsum(v * v);
    if (tid == 0){
      bnpart[(oc0 + o) * 400 + (b * 100 + blockIdx.x) * 2]     = S;
      bnpart[(oc0 + o) * 400 + (b * 100 + blockIdx.x) * 2 + 1] = Q;
    }
  }
}

// ---------------- K13: BN+relu both halves, sum ----------------
__global__ __launch_bounds__(256) void k_ssum(
    const float* __restrict__ bdpre, const float* __restrict__ bnsc,
    float* __restrict__ ssum){
  int tid = threadIdx.x; int c = blockIdx.y, b = blockIdx.z;
  int n = blockIdx.x * 256 + tid;
  float v1 = bdpre[(b * 32 + c) * HW + n] * bnsc[c * 2] + bnsc[c * 2 + 1];
  float v2 = bdpre[(b * 32 + 16 + c) * HW + n] * bnsc[(16 + c) * 2] + bnsc[(16 + c) * 2 + 1];
  ssum[(b * 16 + c) * HW + n] = fmaxf(v1, 0.f) + fmaxf(v2, 0.f);
}

// ---------------- K14: 1x1 conv 16->256 + bias + relu -> out ----------------
__global__ __launch_bounds__(256) void k_c6(
    const float* __restrict__ ssum, const float* __restrict__ w6,
    const float* __restrict__ b6, float* __restrict__ out){
  int tid = threadIdx.x; int og = blockIdx.y * 4, b = blockIdx.z;
  int n = blockIdx.x * 256 + tid;
  float x[16];
  #pragma unroll
  for (int c = 0; c < 16; c++) x[c] = ssum[(b * 16 + c) * HW + n];
  #pragma unroll
  for (int o = 0; o < 4; o++){
    float a = b6[og + o];
    #pragma unroll
    for (int c = 0; c < 16; c++) a += w6[(og + o) * 16 + c] * x[c];
    out[(b * 256 + og + o) * HW + n] = fmaxf(a, 0.f);
  }
}

extern "C" void kernel_launch(void* const* d_in, const int* in_sizes, int n_in,
                              void* d_out, int out_size, void* d_ws, size_t ws_size,
                              hipStream_t stream){
  const float* z      = (const float*)d_in[0];
  const float* w_at0  = (const float*)d_in[1];
  const float* b_at0  = (const float*)d_in[2];
  const float* w_at1  = (const float*)d_in[3];
  const float* b_at1  = (const float*)d_in[4];
  const float* w_at2  = (const float*)d_in[5];
  const float* b_at2  = (const float*)d_in[6];
  const float* w_at3  = (const float*)d_in[7];
  const float* b_at3  = (const float*)d_in[8];
  const float* gn_w   = (const float*)d_in[9];
  const float* gn_b   = (const float*)d_in[10];
  const float* conv_w = (const float*)d_in[11];
  const float* conv_b = (const float*)d_in[12];
  const float* c5a_w  = (const float*)d_in[13];
  const float* bn5a_w = (const float*)d_in[14];
  const float* bn5a_b = (const float*)d_in[15];
  const float* c5c_w  = (const float*)d_in[16];
  const float* bn5c_w = (const float*)d_in[17];
  const float* bn5c_b = (const float*)d_in[18];
  const float* pq_w   = (const float*)d_in[19];
  const float* pq_b   = (const float*)d_in[20];
  const float* pk_w   = (const float*)d_in[21];
  const float* pk_b   = (const float*)d_in[22];
  const float* pv_w   = (const float*)d_in[23];
  const float* pv_b   = (const float*)d_in[24];
  const float* pa_g   = (const float*)d_in[25];
  const float* ca_g   = (const float*)d_in[26];
  const float* c5b_w  = (const float*)d_in[27];
  const float* bn5b_w = (const float*)d_in[28];
  const float* bn5b_b = (const float*)d_in[29];
  const float* c5d_w  = (const float*)d_in[30];
  const float* bn5d_w = (const float*)d_in[31];
  const float* bn5d_b = (const float*)d_in[32];
  const float* c6_w   = (const float*)d_in[33];
  const float* c6_b   = (const float*)d_in[34];

  float* ws = (float*)d_ws;
  float* ZC      = ws;                    // 3,276,800
  float* ZC2     = ZC + 3276800;          // 3,276,800
  float* FPRE    = ZC2 + 3276800;         // 409,600
  float* FEAT    = FPRE + 409600;         // 409,600
  float* QKVT    = FEAT + 409600;         // 256,000
  float* PAM_IN  = QKVT + 256000;         // 204,800
  float* CAM_IN  = PAM_IN + 204800;       // 204,800
  float* BDPRE   = CAM_IN + 204800;       // 409,600
  float* SSUM    = BDPRE + 409600;        // 204,800
  float* ST      = SSUM + 204800;
  float* GN_SC    = ST;                   // 1024
  float* BNA_SC   = ST + 1024;            // 64
  float* BNB_SC   = ST + 1088;            // 64
  float* CAM_ATT  = ST + 1152;            // 512
  float* CAM_E    = ST + 1664;            // 512
  float* GN_PART  = ST + 2176;            // 25,600
  float* BNA_PART = ST + 27776;           // 3,200
  float* BNB_PART = ST + 30976;           // 12,800
  // Aliases into the ZC/ZC2 region:
  //  - PARTIAL (conv5ac split-K, 3,276,800 floats) lives in ZC; ZC dead after k_conv1.
  //  - PART (PAM partials, 16 chunks * 18 planes * 2b * HW = 3,686,400 floats) starts at
  //    ws base and spills into ZC2's space; both ZC and ZC2 are dead before k_pam_a.
  float* PARTIAL = ZC;
  float* PART    = ZC;

  k_dw<<<dim3(25, 256, 2), 256, 0, stream>>>(z, w_at0, b_at0, w_at1, b_at1,
                                             w_at2, b_at2, w_at3, b_at3, ZC, GN_PART);
  k_gnfin<<<8, 256, 0, stream>>>(GN_PART, gn_w, gn_b, GN_SC);
  k_conv1<<<dim3(25, 16, 2), 256, 0, stream>>>(ZC, GN_SC, conv_w, conv_b, ZC2);
  k_conv5ac_part<<<dim3(100, 8, 2), 64, 0, stream>>>(ZC2, c5a_w, c5c_w, PARTIAL);
  k_conv5ac_red<<<dim3(25, 32, 2), 256, 0, stream>>>(PARTIAL, FPRE, BNA_PART);
  k_bnfin<<<1, 256, 0, stream>>>(BNA_PART, 50, bn5a_w, bn5a_b, bn5c_w, bn5c_b, BNA_SC);
  k_featqkv<<<dim3(25, 2), 256, 0, stream>>>(FPRE, BNA_SC, pq_w, pq_b, pk_w, pk_b,
                                             pv_w, pv_b, FEAT, QKVT);
  k_pam_a<<<dim3(25, 16, 2), 256, 0, stream>>>(QKVT, PART);
  k_pam_b<<<dim3(25, 2), 256, 0, stream>>>(PART, FEAT, pa_g, PAM_IN);
  k_cam_gram<<<dim3(16, 16, 2), 256, 0, stream>>>(FEAT, CAM_E);
  k_cam_soft<<<1, 64, 0, stream>>>(CAM_E, CAM_ATT);
  k_cam_apply<<<dim3(25, 16, 2), 256, 0, stream>>>(CAM_ATT, FEAT, ca_g, CAM_IN);
  k_conv5bd2<<<dim3(100, 8, 2), 64, 0, stream>>>(PAM_IN, CAM_IN, c5b_w, c5d_w, BDPRE, BNB_PART);
  k_bnfin<<<1, 256, 0, stream>>>(BNB_PART, 200, bn5b_w, bn5b_b, bn5d_w, bn5d_b, BNB_SC);
  k_ssum<<<dim3(25, 16, 2), 256, 0, stream>>>(BDPRE, BNB_SC, SSUM);
  k_c6<<<dim3(25, 64, 2), 256, 0, stream>>>(SSUM, c6_w, c6_b, (float*)d_out);
}